// Round 4
// baseline (723.699 us; speedup 1.0000x reference)
//
#include <hip/hip_runtime.h>
#include <math.h>

// Problem: B=1024, S=512, D=200, A=100
//   uit = tanh(x@W + b); ait = exp(uit@u); ait /= (sum_s ait + EPS)
//   out[b,d] = sum_s x[b,s,d]*ait[b,s]
//
// R4: drop LDS staging of x entirely. 8192 blocks (b x 8 chunks of 64 rows):
//  - A-fragments for the fp16 MFMA load DIRECTLY from global x (fp32->cvt):
//    per (m,k) the wave covers 16 rows x 128B contiguous -> coalesced.
//    W^T (fp16, zero-padded k>=200) makes padded-k A values harmless; only
//    k=6, lq>=1 is masked (OOB guard).
//  - pool re-reads x fp32 from global (L1/L2-hot lines).
//  - LDS = 1.3KB score buffers only; no staging syncs; each wave is an
//    independent stream of 56 ILP-exposed loads (no convoy, no spill).

typedef _Float16 half8 __attribute__((ext_vector_type(8)));
typedef float float4_ __attribute__((ext_vector_type(4)));

#define B_   1024
#define S_   512
#define D_   200
#define A_   100
#define NPAD 128
#define KPAD 224
#define SC   64          // s-rows per block
#define NCH  (S_ / SC)   // 8 chunks per batch

#define WT_BYTES (NPAD * KPAD * 2)
#define UB_BYTES (NPAD * 2 * 4)
#define NUM_OFF  (WT_BYTES + UB_BYTES)                      // float num[8192][4][200]
#define DEN_OFF  (NUM_OFF + (size_t)B_ * NCH * 4 * D_ * 4)  // float den[8192]

// DPP row_shr add chain: lane 15 of each 16-lane row ends with the row sum.
#define DPP_ADD(v, ctrl)                                                     \
  v += __builtin_bit_cast(float, __builtin_amdgcn_update_dpp(                \
           0, __builtin_bit_cast(int, v), (ctrl), 0xF, 0xF, true))

__global__ void prep_kernel(const float* __restrict__ W,
                            const float* __restrict__ bias,
                            const float* __restrict__ u,
                            void* __restrict__ ws) {
  _Float16* wt = (_Float16*)ws;
  float* upad = (float*)((char*)ws + WT_BYTES);
  float* bpad = upad + NPAD;
  int idx = blockIdx.x * 256 + threadIdx.x;
  if (idx < NPAD * KPAD) {
    int n = idx / KPAD;
    int k = idx % KPAD;
    float v = (n < A_ && k < D_) ? W[k * A_ + n] : 0.f;
    wt[idx] = (_Float16)v;
  }
  if (blockIdx.x == 0 && threadIdx.x < NPAD) {
    int t = threadIdx.x;
    upad[t] = (t < A_) ? u[t] : 0.f;
    bpad[t] = (t < A_) ? bias[t] : 0.f;
  }
}

__global__ __launch_bounds__(256, 4)
void attn_kernel(const float* __restrict__ x,
                 void* __restrict__ ws) {
  __shared__ float score_part[4][SC];
  __shared__ float e_lds[SC];

  const int blk  = blockIdx.x;            // b*8 + chunk
  const int b    = blk >> 3;
  const int chunk= blk & 7;
  const int tid  = threadIdx.x;
  const int lane = tid & 63;
  const int wave = tid >> 6;
  const int lm   = lane & 15;
  const int lq   = lane >> 4;

  const _Float16* wt = (const _Float16*)ws;
  const float* upad = (const float*)((const char*)ws + WT_BYTES);
  const float* bpad = upad + NPAD;
  float* num_out = (float*)((char*)ws + NUM_OFF);
  float* den_out = (float*)((char*)ws + DEN_OFF);

  // ---- Preload W B-fragments: wave w owns n-tiles {2w, 2w+1}.
  half8 Bfrag[2][7];
  float ureg[2], breg[2];
#pragma unroll
  for (int nn = 0; nn < 2; ++nn) {
    int a = (2 * wave + nn) * 16 + lm;
#pragma unroll
    for (int k = 0; k < 7; ++k)
      Bfrag[nn][k] = *(const half8*)(wt + (size_t)a * KPAD + k * 32 + lq * 8);
    ureg[nn] = upad[a];
    breg[nn] = bpad[a];
  }

  const float* xg = x + ((size_t)b * S_ + (size_t)chunk * SC) * D_;  // 64x200 tile

  // ---- MFMA: uit-chunk = x_chunk @ W (64 x 128, K=224), A-frags from global.
  // A-frag (16x16x32): A[m=lane&15][k=lq*8+j] -> row m*16+lm, cols k*32+lq*8..+8.
  float4_ acc[4][2];
#pragma unroll
  for (int m = 0; m < 4; ++m)
#pragma unroll
    for (int nn = 0; nn < 2; ++nn)
      acc[m][nn] = (float4_){0.f, 0.f, 0.f, 0.f};

#pragma unroll
  for (int k = 0; k < 7; ++k) {
#pragma unroll
    for (int m = 0; m < 4; ++m) {
      half8 af = {(_Float16)0.f, (_Float16)0.f, (_Float16)0.f, (_Float16)0.f,
                  (_Float16)0.f, (_Float16)0.f, (_Float16)0.f, (_Float16)0.f};
      if (k < 6 || lq == 0) {   // k=6,lq>0 -> cols>=200: OOB; W is 0 there anyway
        const float* p = xg + (m * 16 + lm) * D_ + k * 32 + lq * 8;
        float4_ lo = *(const float4_*)p;
        float4_ hi = *(const float4_*)(p + 4);
        af[0] = (_Float16)lo.x; af[1] = (_Float16)lo.y;
        af[2] = (_Float16)lo.z; af[3] = (_Float16)lo.w;
        af[4] = (_Float16)hi.x; af[5] = (_Float16)hi.y;
        af[6] = (_Float16)hi.z; af[7] = (_Float16)hi.w;
      }
#pragma unroll
      for (int nn = 0; nn < 2; ++nn)
        acc[m][nn] = __builtin_amdgcn_mfma_f32_16x16x32_f16(
            af, Bfrag[nn][k], acc[m][nn], 0, 0, 0);
    }
  }

  // ---- Epilogue: tanh(c + b[a]) * u[a]; DPP row-reduce over the 16 cols.
  // C/D layout: col(a)=lm, row(s_local)=m*16+lq*4+r. Lane lm==15 holds sums.
#pragma unroll
  for (int m = 0; m < 4; ++m) {
#pragma unroll
    for (int r = 0; r < 4; ++r) {
      float v = 0.f;
#pragma unroll
      for (int nn = 0; nn < 2; ++nn) {
        float z  = acc[m][nn][r] + breg[nn];
        float az = fabsf(z);
        float ez = __expf(az + az);
        float rc = __builtin_amdgcn_rcpf(ez + 1.f);
        float t  = fmaf(-2.f, rc, 1.f);
        t = copysignf(t, z);
        v = fmaf(t, ureg[nn], v);
      }
      DPP_ADD(v, 0x111);
      DPP_ADD(v, 0x112);
      DPP_ADD(v, 0x114);
      DPP_ADD(v, 0x118);
      if (lm == 15) score_part[wave][m * 16 + lq * 4 + r] = v;
    }
  }
  __syncthreads();

  // ---- e_s = exp(score) (faithful: no max-subtract); block denominator.
  if (tid < SC) {
    float ssum = score_part[0][tid] + score_part[1][tid] +
                 score_part[2][tid] + score_part[3][tid];
    float e = __expf(ssum);
    e_lds[tid] = e;
    float d = e;
    d += __shfl_xor(d, 1);
    d += __shfl_xor(d, 2);
    d += __shfl_xor(d, 4);
    d += __shfl_xor(d, 8);
    d += __shfl_xor(d, 16);
    d += __shfl_xor(d, 32);
    if (tid == 0) den_out[blk] = d;
  }
  __syncthreads();

  // ---- Pool (fp32, global re-read, L1/L2-hot): wave w owns s in [16w,16w+16).
  if (lane < 50) {
    float4_ accv = {0.f, 0.f, 0.f, 0.f};
#pragma unroll
    for (int i = 0; i < 16; ++i) {
      int s = wave * 16 + i;
      float e = e_lds[s];
      float4_ v = *(const float4_*)(xg + s * D_ + lane * 4);
      accv.x = fmaf(e, v.x, accv.x);
      accv.y = fmaf(e, v.y, accv.y);
      accv.z = fmaf(e, v.z, accv.z);
      accv.w = fmaf(e, v.w, accv.w);
    }
    *(float4_*)(&num_out[((size_t)blk * 4 + wave) * D_ + lane * 4]) = accv;
  }
}

__global__ __launch_bounds__(256)
void reduce_kernel(const void* __restrict__ ws, float* __restrict__ out) {
  const float* num = (const float*)((const char*)ws + NUM_OFF);
  const float* den = (const float*)((const char*)ws + DEN_OFF);
  int b = blockIdx.x;
  int tid = threadIdx.x;
  if (tid < D_) {
    float d = 0.f;
#pragma unroll
    for (int c = 0; c < NCH; ++c) d += den[b * NCH + c];
    float s = 0.f;
#pragma unroll
    for (int j = 0; j < NCH * 4; ++j)
      s += num[((size_t)b * NCH * 4 + j) * D_ + tid];
    out[(size_t)b * D_ + tid] = s / (d + 1e-7f);
  }
}

extern "C" void kernel_launch(void* const* d_in, const int* in_sizes, int n_in,
                              void* d_out, int out_size, void* d_ws, size_t ws_size,
                              hipStream_t stream) {
  const float* x = (const float*)d_in[0];
  const float* W = (const float*)d_in[1];
  const float* b = (const float*)d_in[2];
  const float* u = (const float*)d_in[3];
  float* out = (float*)d_out;

  int prep_elems = NPAD * KPAD;
  int prep_blocks = (prep_elems + 255) / 256;
  prep_kernel<<<prep_blocks, 256, 0, stream>>>(W, b, u, d_ws);
  attn_kernel<<<B_ * NCH, 256, 0, stream>>>(x, d_ws);
  reduce_kernel<<<B_, 256, 0, stream>>>(d_ws, out);
}